// Round 23
// baseline (84.340 us; speedup 1.0000x reference)
//
#include <hip/hip_runtime.h>

#define BB 2
#define NN 16384
#define KK 4096
#define CC 128
#define SS 32
#define BKK (BB * KK)

typedef float vfloat4 __attribute__((ext_vector_type(4)));

// ---------------------------------------------------------------------------
// Kernel 1: prep + sort, fused across blocks (33 blocks x 1024 threads).
// UNCHANGED from round 20 (champion). Block 0 = r14 counting sort (1-level
// key); blocks 1-32 = xyzw prep (exact reference float exprs, absmax 0.0).
// ---------------------------------------------------------------------------
__global__ __launch_bounds__(1024) void prep_sort_kernel(
    const float* __restrict__ xyz, const float* __restrict__ new_xyz,
    float* __restrict__ xyzw, int* __restrict__ qmap)
{
    const int t = threadIdx.x;

    if (blockIdx.x == 0) {
        __shared__ int hist[64];
        __shared__ int base[64];
        __shared__ unsigned char bk[BKK];    // 8 KB

        if (t < 64) hist[t] = 0;
        __syncthreads();

#pragma unroll
        for (int c = 0; c < BKK / 1024; ++c) {
            const int q = c * 1024 + t;
            const float* p = new_xyz + (size_t)q * 3;
            const float qq = p[0] * p[0] + p[1] * p[1] + p[2] * p[2];
            int bkt = (int)(qq * 8.0f);
            bkt = bkt > 63 ? 63 : bkt;
            bk[q] = (unsigned char)bkt;
            atomicAdd(&hist[bkt], 1);
        }
        __syncthreads();

        if (t == 0) {
            int s = 0;
#pragma unroll
            for (int i = 0; i < 64; ++i) { base[i] = s; s += hist[i]; }
        }
        __syncthreads();

#pragma unroll
        for (int c = 0; c < BKK / 1024; ++c) {
            const int q = c * 1024 + t;
            const int pos = atomicAdd(&base[bk[q]], 1);
            qmap[pos] = q;
        }
    } else {
        const int i = (blockIdx.x - 1) * 1024 + t;
        const float* p = xyz + (size_t)i * 3;
        const float x = p[0], y = p[1], z = p[2];
        const float pp = __fadd_rn(__fadd_rn(__fmul_rn(x, x), __fmul_rn(y, y)),
                                   __fmul_rn(z, z));
        vfloat4 v = {x, y, z, pp};
        *(vfloat4*)(xyzw + (size_t)i * 4) = v;
    }
}

// ---------------------------------------------------------------------------
// Kernel 2: ball ∥ transpose, 128-THREAD blocks. Ball body verbatim but
// 2 waves/block (qi = qmap[blk*2+wave]): exit granularity = max-of-2
// sorted-adjacent (~equal) scan lengths instead of max-of-4 — attacks the
// 58% occupancy from r13's probe without sacrificing TLP (4096 blocks x 2
// waves <= 16 blocks/CU -> full 32 waves/CU). Transpose = 32-row tile at
// 128 threads (8+8 iters). Ball blocks dispatch first.
// ---------------------------------------------------------------------------
__global__ __launch_bounds__(128) void ball_transpose_kernel(
    const float* __restrict__ xyzw,      // [B][N][4]
    const float* __restrict__ new_xyz,   // [B][K][3]
    const int* __restrict__ qmap,        // [BKK]
    const float* __restrict__ feat,      // [B][C][N]
    int* __restrict__ idx_buf,           // [BKK][S]
    float* __restrict__ feat_t)          // [B][N][C]
{
    __shared__ float tile[32][133];      // 17 KB (transpose blocks only)

    const int t = threadIdx.x;

    if (blockIdx.x < BKK / 2) {
        // ------------------ ball query (champion body, 2 waves) --------------
        const int wave = t >> 6;             // 0..1
        const int lane = t & 63;
        const int qi   = qmap[blockIdx.x * 2 + wave];
        const int b    = qi >> 12;           // K = 4096
        const int k    = qi & (KK - 1);

        const float R2 = (float)(0.4 * 0.4);

        const float* q = new_xyz + (size_t)(b * KK + k) * 3;
        const float qx = q[0], qy = q[1], qz = q[2];
        const float qq = __fadd_rn(__fadd_rn(__fmul_rn(qx, qx), __fmul_rn(qy, qy)),
                                   __fmul_rn(qz, qz));

        const vfloat4* xw = (const vfloat4*)xyzw + (size_t)b * NN;
        int* out = idx_buf + (size_t)qi * SS;

        int cnt = 0;
        int first = -1;

        auto process = [&](int base, vfloat4 v) {
            const float dot = __fadd_rn(__fadd_rn(__fmul_rn(qx, v.x), __fmul_rn(qy, v.y)),
                                        __fmul_rn(qz, v.z));
            const float d2 = __fsub_rn(__fadd_rn(qq, v.w), __fmul_rn(2.0f, dot));
            const bool inball = d2 < R2;
            const unsigned long long mask = __ballot(inball);
            if (mask) {
                if (first < 0) first = base + (int)__builtin_ctzll(mask);
                if (inball) {
                    const int pos = cnt + __popcll(mask & ((1ull << lane) - 1ull));
                    if (pos < SS) out[pos] = base + lane;
                }
                cnt += __popcll(mask);
            }
        };

        vfloat4 v0 = xw[lane];
        vfloat4 v1 = xw[64 + lane];
        vfloat4 v2 = xw[128 + lane];
        vfloat4 v3 = xw[192 + lane];

        for (int base = 0; base < NN; base += 256) {
            const int nb = (base + 256 < NN) ? base + 256 : 0;   // clamp; unused
            vfloat4 u0 = xw[nb + lane];
            vfloat4 u1 = xw[nb + 64 + lane];
            vfloat4 u2 = xw[nb + 128 + lane];
            vfloat4 u3 = xw[nb + 192 + lane];

            process(base, v0);
            process(base + 64, v1);
            process(base + 128, v2);
            process(base + 192, v3);
            if (cnt >= SS) break;

            v0 = u0; v1 = u1; v2 = u2; v3 = u3;
        }

        const int fill = (first < 0) ? 0 : first;
        if (lane < SS && lane >= cnt) out[lane] = fill;
    } else {
        // ------------------ transpose, 32-row tile, 128 threads --------------
        const int tb = blockIdx.x - BKK / 2;     // 0..1023
        const int b  = tb >> 9;                  // NN/32 = 512 tiles per batch
        const int n0 = (tb & 511) * 32;

        // Read: 1024 float4 loads (c 0..127, n-quad 0..7), 8 iters x 128 thr.
#pragma unroll
        for (int i = 0; i < 8; ++i) {
            const int li = i * 128 + t;
            const int c  = li >> 3;
            const int n4 = (li & 7) * 4;
            const vfloat4 v = *(const vfloat4*)(feat + ((size_t)b * CC + c) * NN + n0 + n4);
            tile[n4 + 0][c] = v.x;
            tile[n4 + 1][c] = v.y;
            tile[n4 + 2][c] = v.z;
            tile[n4 + 3][c] = v.w;
        }
        __syncthreads();

        // Write: 1024 float4 stores (n 0..31, c-quad 0..31), 8 iters x 128 thr.
#pragma unroll
        for (int i = 0; i < 8; ++i) {
            const int li = i * 128 + t;
            const int n  = li >> 5;
            const int c4 = (li & 31) * 4;
            vfloat4 v;
            v.x = tile[n][c4 + 0];
            v.y = tile[n][c4 + 1];
            v.z = tile[n][c4 + 2];
            v.w = tile[n][c4 + 3];
            *(vfloat4*)(feat_t + ((size_t)(b * NN + n0 + n)) * CC + c4) = v;
        }
    }
}

// ---------------------------------------------------------------------------
// Kernel 3: grouping — 2-tile software pipeline. Per block: tiles bk0=2*bid,
// bk1=bk0+1 (bk0 even -> pair never straddles a batch). Stage A -> barrier ->
// {issue stage B DMAs + txyzB} -> write A (B's HBM latency hides under A's
// stores) -> barrier (drains B) -> write B. Swizzle/write bodies verbatim
// from the r10-validated form. LDS 33KB -> 4 blocks/CU (stores saturate at
// ~10% occupancy per fill-kernel evidence).
// ---------------------------------------------------------------------------
__global__ __launch_bounds__(256) void group_kernel(
    const float* __restrict__ xyzw,      // [B][N][4]
    const float* __restrict__ new_xyz,   // [B][K][3]
    const float* __restrict__ feat_t,    // [B][N][C]
    const int*   __restrict__ idx_buf,   // [BKK][S]
    float* __restrict__ out)             // [B][3][K][S] ++ [B][C][K][S]
{
    __shared__ float tileA[SS * CC];     // 16 KB, linear, chunk-swizzled
    __shared__ float tileB[SS * CC];     // 16 KB
    __shared__ float txyzA[3][SS];
    __shared__ float txyzB[3][SS];

    const int t    = threadIdx.x;
    const int l    = t & 63;
    const int w    = t >> 6;             // wave 0..3
    const int bk0  = blockIdx.x * 2;
    const int bk1  = bk0 + 1;
    const int half = l >> 5;             // 0..1
    const int cl   = l & 31;             // chunk slot within row

    float* out_xyz  = out;
    float* out_feat = out + (size_t)BB * 3 * KK * SS;

    // ---- stage A ----
    {
        const int b = bk0 >> 12;
#pragma unroll
        for (int p = 0; p < 4; ++p) {
            const int r = 8 * w + 2 * p;
            const int s = r + half;
            const int n = idx_buf[bk0 * SS + s];
            const int chunk = cl ^ ((s >> 2) & 7);
            const float* src = feat_t + ((size_t)(b * NN + n)) * CC + 4 * chunk;
            __builtin_amdgcn_global_load_lds(
                (const __attribute__((address_space(1))) void*)src,
                (__attribute__((address_space(3))) void*)(tileA + r * CC),
                16, 0, 0);
        }
        if (t < SS) {
            const int n = idx_buf[bk0 * SS + t];
            const float* q = new_xyz + (size_t)bk0 * 3;
            const vfloat4 wv = *((const vfloat4*)xyzw + (size_t)b * NN + n);
            txyzA[0][t] = (wv.x - q[0]) / 0.4f;
            txyzA[1][t] = (wv.y - q[1]) / 0.4f;
            txyzA[2][t] = (wv.z - q[2]) / 0.4f;
        }
    }

    __syncthreads();   // drains A DMAs + txyzA

    // ---- issue stage B (flies under write A) ----
    {
        const int b = bk1 >> 12;
#pragma unroll
        for (int p = 0; p < 4; ++p) {
            const int r = 8 * w + 2 * p;
            const int s = r + half;
            const int n = idx_buf[bk1 * SS + s];
            const int chunk = cl ^ ((s >> 2) & 7);
            const float* src = feat_t + ((size_t)(b * NN + n)) * CC + 4 * chunk;
            __builtin_amdgcn_global_load_lds(
                (const __attribute__((address_space(1))) void*)src,
                (__attribute__((address_space(3))) void*)(tileB + r * CC),
                16, 0, 0);
        }
        if (t < SS) {
            const int n = idx_buf[bk1 * SS + t];
            const float* q = new_xyz + (size_t)bk1 * 3;
            const vfloat4 wv = *((const vfloat4*)xyzw + (size_t)b * NN + n);
            txyzB[0][t] = (wv.x - q[0]) / 0.4f;
            txyzB[1][t] = (wv.y - q[1]) / 0.4f;
            txyzB[2][t] = (wv.z - q[2]) / 0.4f;
        }
    }

    // ---- write A ----
    {
        const int b  = bk0 >> 12;
        const int k  = bk0 & (KK - 1);
        const int sq = t & 7;
        const int c0 = t >> 3;
#pragma unroll
        for (int p = 0; p < 4; ++p) {
            const int c  = c0 + 32 * p;
            const int co = (((c >> 2) ^ sq) << 2) + (c & 3);
            vfloat4 v;
            v.x = tileA[(4 * sq + 0) * CC + co];
            v.y = tileA[(4 * sq + 1) * CC + co];
            v.z = tileA[(4 * sq + 2) * CC + co];
            v.w = tileA[(4 * sq + 3) * CC + co];
            __builtin_nontemporal_store(
                v, (vfloat4*)(out_feat + (((size_t)(b * CC + c) * KK + k) * SS + 4 * sq)));
        }
        if (t < 24) {
            const int d   = t >> 3;
            const int sq2 = t & 7;
            const vfloat4 v = *(vfloat4*)&txyzA[d][4 * sq2];
            __builtin_nontemporal_store(
                v, (vfloat4*)(out_xyz + (((size_t)(b * 3 + d) * KK + k) * SS + 4 * sq2)));
        }
    }

    __syncthreads();   // drains B DMAs + txyzB

    // ---- write B ----
    {
        const int b  = bk1 >> 12;
        const int k  = bk1 & (KK - 1);
        const int sq = t & 7;
        const int c0 = t >> 3;
#pragma unroll
        for (int p = 0; p < 4; ++p) {
            const int c  = c0 + 32 * p;
            const int co = (((c >> 2) ^ sq) << 2) + (c & 3);
            vfloat4 v;
            v.x = tileB[(4 * sq + 0) * CC + co];
            v.y = tileB[(4 * sq + 1) * CC + co];
            v.z = tileB[(4 * sq + 2) * CC + co];
            v.w = tileB[(4 * sq + 3) * CC + co];
            __builtin_nontemporal_store(
                v, (vfloat4*)(out_feat + (((size_t)(b * CC + c) * KK + k) * SS + 4 * sq)));
        }
        if (t < 24) {
            const int d   = t >> 3;
            const int sq2 = t & 7;
            const vfloat4 v = *(vfloat4*)&txyzB[d][4 * sq2];
            __builtin_nontemporal_store(
                v, (vfloat4*)(out_xyz + (((size_t)(b * 3 + d) * KK + k) * SS + 4 * sq2)));
        }
    }
}

extern "C" void kernel_launch(void* const* d_in, const int* in_sizes, int n_in,
                              void* d_out, int out_size, void* d_ws, size_t ws_size,
                              hipStream_t stream) {
    const float* xyz     = (const float*)d_in[0];   // [2][16384][3]
    const float* new_xyz = (const float*)d_in[1];   // [2][4096][3]
    const float* feat    = (const float*)d_in[2];   // [2][128][16384]
    float* out = (float*)d_out;

    // Workspace: idx_buf 1MB | xyzw 0.5MB | feat_t 16MB | qmap 32KB
    int*   idx_buf = (int*)d_ws;
    float* xyzw    = (float*)((char*)d_ws + (1 << 20));
    float* feat_t  = (float*)((char*)d_ws + (1 << 20) + (512 << 10));
    int*   qmap    = (int*)((char*)d_ws + (1 << 20) + (512 << 10) + (CC * NN * BB) * 4);

    // 1: prep (blocks 1-32) ∥ qsort (block 0)
    prep_sort_kernel<<<dim3(33), dim3(1024), 0, stream>>>(
        xyz, new_xyz, xyzw, qmap);

    // 2: ball (blocks 0-4095, 2 waves each, dispatched first) ∥ transpose
    ball_transpose_kernel<<<dim3(BKK / 2 + BB * (NN / 32)), dim3(128), 0, stream>>>(
        xyzw, new_xyz, qmap, feat, idx_buf, feat_t);

    // 3: group, 2-tile pipeline (4096 blocks)
    group_kernel<<<dim3(BKK / 2), dim3(256), 0, stream>>>(
        xyzw, new_xyz, feat_t, idx_buf, out);
}

// Round 24
// 83.154 us; speedup vs baseline: 1.0143x; 1.0143x over previous
//
#include <hip/hip_runtime.h>

#define BB 2
#define NN 16384
#define KK 4096
#define CC 128
#define SS 32
#define BKK (BB * KK)

typedef float vfloat4 __attribute__((ext_vector_type(4)));

// ---------------------------------------------------------------------------
// CHAMPION CONFIG (round 20, 82.7us, absmax 0.0) — restored verbatim.
// r23's refinements (2-wave ball blocks, 2-tile group pipeline) measured
// +1.6us combined and are reverted per pre-commitment.
// ---------------------------------------------------------------------------

// Kernel 1: prep + sort, fused across blocks (33 blocks x 1024 threads).
// Block 0 = r14 counting sort (1-level key); blocks 1-32 = xyzw prep.
__global__ __launch_bounds__(1024) void prep_sort_kernel(
    const float* __restrict__ xyz, const float* __restrict__ new_xyz,
    float* __restrict__ xyzw, int* __restrict__ qmap)
{
    const int t = threadIdx.x;

    if (blockIdx.x == 0) {
        __shared__ int hist[64];
        __shared__ int base[64];
        __shared__ unsigned char bk[BKK];    // 8 KB

        if (t < 64) hist[t] = 0;
        __syncthreads();

#pragma unroll
        for (int c = 0; c < BKK / 1024; ++c) {
            const int q = c * 1024 + t;
            const float* p = new_xyz + (size_t)q * 3;
            const float qq = p[0] * p[0] + p[1] * p[1] + p[2] * p[2];
            int bkt = (int)(qq * 8.0f);
            bkt = bkt > 63 ? 63 : bkt;
            bk[q] = (unsigned char)bkt;
            atomicAdd(&hist[bkt], 1);
        }
        __syncthreads();

        if (t == 0) {
            int s = 0;
#pragma unroll
            for (int i = 0; i < 64; ++i) { base[i] = s; s += hist[i]; }
        }
        __syncthreads();

#pragma unroll
        for (int c = 0; c < BKK / 1024; ++c) {
            const int q = c * 1024 + t;
            const int pos = atomicAdd(&base[bk[q]], 1);
            qmap[pos] = q;
        }
    } else {
        const int i = (blockIdx.x - 1) * 1024 + t;
        const float* p = xyz + (size_t)i * 3;
        const float x = p[0], y = p[1], z = p[2];
        const float pp = __fadd_rn(__fadd_rn(__fmul_rn(x, x), __fmul_rn(y, y)),
                                   __fmul_rn(z, z));
        vfloat4 v = {x, y, z, pp};
        *(vfloat4*)(xyzw + (size_t)i * 4) = v;
    }
}

// Kernel 2: ball (blocks 0-2047, 4 waves, champion body) ∥ transpose
// (blocks 2048-3071, 32-row tile, 17 KB LDS). 256 threads.
__global__ __launch_bounds__(256) void ball_transpose_kernel(
    const float* __restrict__ xyzw,      // [B][N][4]
    const float* __restrict__ new_xyz,   // [B][K][3]
    const int* __restrict__ qmap,        // [BKK]
    const float* __restrict__ feat,      // [B][C][N]
    int* __restrict__ idx_buf,           // [BKK][S]
    float* __restrict__ feat_t)          // [B][N][C]
{
    __shared__ float tile[32][133];      // 17 KB (transpose blocks only)

    const int t = threadIdx.x;

    if (blockIdx.x < BKK / 4) {
        // ------------------ ball query (champion, verbatim) ------------------
        const int wave = t >> 6;
        const int lane = t & 63;
        const int qi   = qmap[blockIdx.x * 4 + wave];
        const int b    = qi >> 12;                   // K = 4096
        const int k    = qi & (KK - 1);

        const float R2 = (float)(0.4 * 0.4);

        const float* q = new_xyz + (size_t)(b * KK + k) * 3;
        const float qx = q[0], qy = q[1], qz = q[2];
        const float qq = __fadd_rn(__fadd_rn(__fmul_rn(qx, qx), __fmul_rn(qy, qy)),
                                   __fmul_rn(qz, qz));

        const vfloat4* xw = (const vfloat4*)xyzw + (size_t)b * NN;
        int* out = idx_buf + (size_t)qi * SS;

        int cnt = 0;
        int first = -1;

        auto process = [&](int base, vfloat4 v) {
            const float dot = __fadd_rn(__fadd_rn(__fmul_rn(qx, v.x), __fmul_rn(qy, v.y)),
                                        __fmul_rn(qz, v.z));
            const float d2 = __fsub_rn(__fadd_rn(qq, v.w), __fmul_rn(2.0f, dot));
            const bool inball = d2 < R2;
            const unsigned long long mask = __ballot(inball);
            if (mask) {
                if (first < 0) first = base + (int)__builtin_ctzll(mask);
                if (inball) {
                    const int pos = cnt + __popcll(mask & ((1ull << lane) - 1ull));
                    if (pos < SS) out[pos] = base + lane;
                }
                cnt += __popcll(mask);
            }
        };

        vfloat4 v0 = xw[lane];
        vfloat4 v1 = xw[64 + lane];
        vfloat4 v2 = xw[128 + lane];
        vfloat4 v3 = xw[192 + lane];

        for (int base = 0; base < NN; base += 256) {
            const int nb = (base + 256 < NN) ? base + 256 : 0;   // clamp; unused
            vfloat4 u0 = xw[nb + lane];
            vfloat4 u1 = xw[nb + 64 + lane];
            vfloat4 u2 = xw[nb + 128 + lane];
            vfloat4 u3 = xw[nb + 192 + lane];

            process(base, v0);
            process(base + 64, v1);
            process(base + 128, v2);
            process(base + 192, v3);
            if (cnt >= SS) break;

            v0 = u0; v1 = u1; v2 = u2; v3 = u3;
        }

        const int fill = (first < 0) ? 0 : first;
        if (lane < SS && lane >= cnt) out[lane] = fill;
    } else {
        // ------------------ transpose, 32-row tile ------------------
        const int tb = blockIdx.x - BKK / 4;     // 0..1023
        const int b  = tb >> 9;                  // NN/32 = 512 tiles per batch
        const int n0 = (tb & 511) * 32;

        // Read: 1024 float4 loads (c 0..127, n-quad 0..7), 4 iters x 256 thr.
#pragma unroll
        for (int i = 0; i < 4; ++i) {
            const int li = i * 256 + t;
            const int c  = li >> 3;
            const int n4 = (li & 7) * 4;
            const vfloat4 v = *(const vfloat4*)(feat + ((size_t)b * CC + c) * NN + n0 + n4);
            tile[n4 + 0][c] = v.x;
            tile[n4 + 1][c] = v.y;
            tile[n4 + 2][c] = v.z;
            tile[n4 + 3][c] = v.w;
        }
        __syncthreads();

        // Write: 1024 float4 stores (n 0..31, c-quad 0..31), 4 iters x 256 thr.
#pragma unroll
        for (int i = 0; i < 4; ++i) {
            const int li = i * 256 + t;
            const int n  = li >> 5;
            const int c4 = (li & 31) * 4;
            vfloat4 v;
            v.x = tile[n][c4 + 0];
            v.y = tile[n][c4 + 1];
            v.z = tile[n][c4 + 2];
            v.w = tile[n][c4 + 3];
            *(vfloat4*)(feat_t + ((size_t)(b * NN + n0 + n)) * CC + c4) = v;
        }
    }
}

// Kernel 3: grouping, single-tile (r10-validated): gload_lds DMA gather +
// chunk-XOR-swizzled linear LDS (0 bank conflicts) + nontemporal [C][S]
// writes. G~7us + W~24us.
__global__ __launch_bounds__(256) void group_kernel(
    const float* __restrict__ xyzw,      // [B][N][4]
    const float* __restrict__ new_xyz,   // [B][K][3]
    const float* __restrict__ feat_t,    // [B][N][C]
    const int*   __restrict__ idx_buf,   // [BKK][S]
    float* __restrict__ out)             // [B][3][K][S] ++ [B][C][K][S]
{
    __shared__ float tile[SS * CC];      // 16 KB, linear, chunk-swizzled
    __shared__ float txyz[3][SS];

    const int t    = threadIdx.x;
    const int l    = t & 63;
    const int w    = t >> 6;             // wave 0..3
    const int bk   = blockIdx.x;
    const int b    = bk >> 12;
    const int k    = bk & (KK - 1);
    const int half = l >> 5;             // 0..1
    const int cl   = l & 31;             // chunk slot within row

#pragma unroll
    for (int p = 0; p < 4; ++p) {
        const int r = 8 * w + 2 * p;                 // wave-uniform row base
        const int s = r + half;
        const int n = idx_buf[bk * SS + s];
        const int chunk = cl ^ ((s >> 2) & 7);
        const float* src = feat_t + ((size_t)(b * NN + n)) * CC + 4 * chunk;
        __builtin_amdgcn_global_load_lds(
            (const __attribute__((address_space(1))) void*)src,
            (__attribute__((address_space(3))) void*)(tile + r * CC),
            16, 0, 0);
    }

    if (t < SS) {
        const int n = idx_buf[bk * SS + t];
        const float* q = new_xyz + (size_t)bk * 3;
        const vfloat4 wv = *((const vfloat4*)xyzw + (size_t)b * NN + n);
        txyz[0][t] = (wv.x - q[0]) / 0.4f;
        txyz[1][t] = (wv.y - q[1]) / 0.4f;
        txyz[2][t] = (wv.z - q[2]) / 0.4f;
    }

    __syncthreads();   // drains vmcnt(0): all DMAs + txyz visible

    float* out_xyz  = out;
    float* out_feat = out + (size_t)BB * 3 * KK * SS;

    const int sq = t & 7;
    const int c0 = t >> 3;               // 0..31
#pragma unroll
    for (int p = 0; p < 4; ++p) {
        const int c  = c0 + 32 * p;
        const int co = (((c >> 2) ^ sq) << 2) + (c & 3);   // un-swizzled col
        vfloat4 v;
        v.x = tile[(4 * sq + 0) * CC + co];
        v.y = tile[(4 * sq + 1) * CC + co];
        v.z = tile[(4 * sq + 2) * CC + co];
        v.w = tile[(4 * sq + 3) * CC + co];
        __builtin_nontemporal_store(
            v, (vfloat4*)(out_feat + (((size_t)(b * CC + c) * KK + k) * SS + 4 * sq)));
    }

    if (t < 24) {
        const int d   = t >> 3;
        const int sq2 = t & 7;
        const vfloat4 v = *(vfloat4*)&txyz[d][4 * sq2];
        __builtin_nontemporal_store(
            v, (vfloat4*)(out_xyz + (((size_t)(b * 3 + d) * KK + k) * SS + 4 * sq2)));
    }
}

extern "C" void kernel_launch(void* const* d_in, const int* in_sizes, int n_in,
                              void* d_out, int out_size, void* d_ws, size_t ws_size,
                              hipStream_t stream) {
    const float* xyz     = (const float*)d_in[0];   // [2][16384][3]
    const float* new_xyz = (const float*)d_in[1];   // [2][4096][3]
    const float* feat    = (const float*)d_in[2];   // [2][128][16384]
    float* out = (float*)d_out;

    // Workspace: idx_buf 1MB | xyzw 0.5MB | feat_t 16MB | qmap 32KB
    int*   idx_buf = (int*)d_ws;
    float* xyzw    = (float*)((char*)d_ws + (1 << 20));
    float* feat_t  = (float*)((char*)d_ws + (1 << 20) + (512 << 10));
    int*   qmap    = (int*)((char*)d_ws + (1 << 20) + (512 << 10) + (CC * NN * BB) * 4);

    // 1: prep (blocks 1-32) ∥ qsort (block 0)
    prep_sort_kernel<<<dim3(33), dim3(1024), 0, stream>>>(
        xyz, new_xyz, xyzw, qmap);

    // 2: ball (blocks 0-2047, dispatched first) ∥ transpose (blocks 2048-3071)
    ball_transpose_kernel<<<dim3(BKK / 4 + BB * (NN / 32)), dim3(256), 0, stream>>>(
        xyzw, new_xyz, qmap, feat, idx_buf, feat_t);

    // 3: group
    group_kernel<<<dim3(BKK), dim3(256), 0, stream>>>(
        xyzw, new_xyz, feat_t, idx_buf, out);
}